// Round 9
// baseline (3069.680 us; speedup 1.0000x reference)
//
#include <hip/hip_runtime.h>

// RNN-T loss forward: B=8, T=128, U=100, V=1024, BLANK=0.
// Single fused kernel: lse blocks (25856) stream log-softmax into
// diagonal-major staging with release-counters; 8 dp blocks acquire-spin on
// the counters and run the anti-diagonal DP concurrently, hiding the DP under
// the big memory-bound read. Last dp block writes the batch-mean NLL.

#define NEGV (-1e30f)

constexpr int Bb = 8;
constexpr int Tt = 128;
constexpr int Uu = 100;
constexpr int Vv = 1024;
constexpr int UP1 = Uu + 1;
constexpr int DROWS = 244;       // staging rows (d up to 232 + prefetch spill)
constexpr int DPAD  = 104;       // staging row pitch in floats
constexpr int CHUNK = 8;         // diagonals per chunk
constexpr int LPITCH = 128;      // LDS row pitch in floats
constexpr int NDIAG_MAX = 228;   // last real diagonal (t=127,u=100 -> d=228)
constexpr int NB_LSE = (Bb * Tt * UP1) / 4;   // 25856 lse blocks (4 rows each)

__device__ __forceinline__ float laddexp(float x, float y) {
    float m = fmaxf(x, y);
    float d = fabsf(x - y);
    return m + __logf(1.0f + __expf(-d));
}

// lane l receives lane l-1's value; lane 0 -> 0
__device__ __forceinline__ float wave_shr1(float x) {
    return __builtin_bit_cast(float, __builtin_amdgcn_update_dpp(
        0, __builtin_bit_cast(int, x), 0x138, 0xf, 0xf, true));
}

__device__ __forceinline__ float readlane_f(float x, int lane) {
    return __builtin_bit_cast(float,
        __builtin_amdgcn_readlane(__builtin_bit_cast(int, x), lane));
}

// #rows (b fixed) staged into chunk ck = rows d in [8ck+1, 8ck+8], d<=228;
// cnt(d) = #{(t,u): t+u+1=d, 0<=t<=127, 0<=u<=100}
__device__ __forceinline__ int chunk_expected(int ck) {
    int s = 0;
    #pragma unroll
    for (int j = 1; j <= 8; ++j) {
        int d = ck * 8 + j;
        if (d <= NDIAG_MAX) {
            int lo = (d - 101 > 0) ? d - 101 : 0;
            int hi = (d - 1 < 127) ? d - 1 : 127;
            s += hi - lo + 1;
        }
    }
    return s;
}

__global__ __launch_bounds__(256) void fused_kernel(
        const float* __restrict__ logits,
        const int*   __restrict__ targets,
        const int*   __restrict__ logit_lengths,
        const int*   __restrict__ target_lengths,
        int*   __restrict__ cnt,      // [Bb*32] chunk counters (zeroed per call)
        int*   __restrict__ dcnt,     // [1] done counter (zeroed per call)
        float* __restrict__ bS,
        float* __restrict__ eS,
        float* __restrict__ nll,
        float* __restrict__ out) {
    __shared__ float ringB[2][CHUNK][LPITCH];
    __shared__ float ringE[2][CHUNK][LPITCH];

    const int bid = blockIdx.x;

    if (bid < NB_LSE) {
        // ---------------- LSE path: one wave per (b,t,u) row, b-minor -----
        const int wid  = bid * 4 + (threadIdx.x >> 6);
        const int lane = threadIdx.x & 63;
        const int b = wid & 7;
        const int r = wid >> 3;              // 0..12927  (t-major per batch)
        const int t = r / UP1;
        const int u = r - t * UP1;

        const float* row = logits + (size_t)((b * Tt + t) * UP1 + u) * Vv;
        const float4* r4 = (const float4*)row;
        float4 x0 = r4[lane];
        float4 x1 = r4[lane + 64];
        float4 x2 = r4[lane + 128];
        float4 x3 = r4[lane + 192];

        float m = fmaxf(fmaxf(fmaxf(x0.x, x0.y), fmaxf(x0.z, x0.w)),
                        fmaxf(fmaxf(x1.x, x1.y), fmaxf(x1.z, x1.w)));
        m = fmaxf(m, fmaxf(fmaxf(fmaxf(x2.x, x2.y), fmaxf(x2.z, x2.w)),
                           fmaxf(fmaxf(x3.x, x3.y), fmaxf(x3.z, x3.w))));
        #pragma unroll
        for (int d = 32; d > 0; d >>= 1) m = fmaxf(m, __shfl_xor(m, d, 64));

        float s = __expf(x0.x-m) + __expf(x0.y-m) + __expf(x0.z-m) + __expf(x0.w-m)
                + __expf(x1.x-m) + __expf(x1.y-m) + __expf(x1.z-m) + __expf(x1.w-m)
                + __expf(x2.x-m) + __expf(x2.y-m) + __expf(x2.z-m) + __expf(x2.w-m)
                + __expf(x3.x-m) + __expf(x3.y-m) + __expf(x3.z-m) + __expf(x3.w-m);
        #pragma unroll
        for (int d = 32; d > 0; d >>= 1) s += __shfl_xor(s, d, 64);

        float lse = m + __logf(s);

        if (lane == 0) {
            const int dw = t + u + 1;                   // 1..228
            bS[((size_t)b * DROWS + dw) * DPAD + u] = x0.x - lse;  // BLANK
            if (u < Uu) {
                int tgt = targets[b * Uu + u];
                eS[((size_t)b * DROWS + dw) * DPAD + (u + 1)] = row[tgt] - lse;
            }
            // release: staging stores above are visible before the count.
            __hip_atomic_fetch_add(&cnt[b * 32 + ((dw - 1) >> 3)], 1,
                                   __ATOMIC_RELEASE, __HIP_MEMORY_SCOPE_AGENT);
        }
        return;
    }

    // ---------------- DP path: 8 blocks, wave0=consumer, wave1=producer ---
    const int b    = bid - NB_LSE;
    const int tid  = threadIdx.x;
    const int wv   = tid >> 6;          // 0=consumer, 1=producer, 2-3=barrier-only
    const int lane = tid & 63;
    const float* bB = bS + (size_t)b * DROWS * DPAD;
    const float* eB = eS + (size_t)b * DROWS * DPAD;
    const int tl = logit_lengths[b];
    const int ul = target_lengths[b];
    const int t_idx = tl - 2;           // reference reads alpha[tl-2][ul]
    const int dcap  = t_idx + ul;       // diagonal of the readout cell

    // consumer state
    const int u0 = lane * 2, u1 = u0 + 1;
    float aP0 = (lane == 0) ? 0.0f : NEGV;   // alpha diag 0: only (0,0)=0
    float aP1 = NEGV;
    float cap = (dcap == 0) ? 0.0f : NEGV;

    // producer state: two register sets (chunk k lives in set k&1)
    float2 LAb[CHUNK], LAe[CHUNK], LBb[CHUNK], LBe[CHUNK];

#define GATE(ck) do {                                                        \
        if (lane == 0) {                                                     \
            const int _exp = chunk_expected(ck);                             \
            while (__hip_atomic_load(&cnt[b * 32 + (ck)], __ATOMIC_ACQUIRE,  \
                                     __HIP_MEMORY_SCOPE_AGENT) < _exp)       \
                __builtin_amdgcn_s_sleep(1);                                 \
        }                                                                    \
    } while (0)

#define PLOAD(SETb, SETe, ck) do {                                           \
        const float* _pb = bB + (size_t)((ck) * CHUNK + 1) * DPAD + lane * 2;\
        const float* _pe = eB + (size_t)((ck) * CHUNK + 1) * DPAD + lane * 2;\
        _Pragma("unroll")                                                    \
        for (int r = 0; r < CHUNK; ++r) {                                    \
            SETb[r] = *(const float2*)(_pb + r * DPAD);                      \
            SETe[r] = *(const float2*)(_pe + r * DPAD);                      \
        }                                                                    \
    } while (0)

#define PWRITE(SETb, SETe, slot) do {                                        \
        _Pragma("unroll")                                                    \
        for (int r = 0; r < CHUNK; ++r) {                                    \
            *(float2*)&ringB[slot][r][lane * 2] = SETb[r];                   \
            *(float2*)&ringE[slot][r][lane * 2] = SETe[r];                   \
        }                                                                    \
    } while (0)

#define CCHUNK(cc, slot) do {                                                \
        float2 Bv[CHUNK], Ev[CHUNK];                                         \
        _Pragma("unroll")                                                    \
        for (int r = 0; r < CHUNK; ++r) {                                    \
            Bv[r] = *(const float2*)&ringB[slot][r][u0];                     \
            Ev[r] = *(const float2*)&ringE[slot][r][u0];                     \
        }                                                                    \
        _Pragma("unroll")                                                    \
        for (int r = 0; r < CHUNK; ++r) {                                    \
            const int dv = (cc) * CHUNK + 1 + r;                             \
            float sh  = wave_shr1(aP1);                                      \
            float t1b = (u1 < dv) ? aP1 + Bv[r].y : NEGV;                    \
            float t1e = aP0 + Ev[r].y;                                       \
            float t0b = (u0 < dv) ? aP0 + Bv[r].x : NEGV;                    \
            float t0e = (lane >= 1) ? sh + Ev[r].x : NEGV;                   \
            float n1 = laddexp(t1b, t1e);                                    \
            float n0 = laddexp(t0b, t0e);                                    \
            aP0 = n0; aP1 = n1;                                              \
            if (dv == dcap) {                                                \
                float w0 = readlane_f(n0, ul >> 1);                          \
                float w1 = readlane_f(n1, ul >> 1);                          \
                cap = (ul & 1) ? w1 : w0;                                    \
            }                                                                \
        }                                                                    \
    } while (0)

    // prologue: producer gates+loads chunks 0,1; writes chunk 0 to slot 0
    if (wv == 1) {
        GATE(0); PLOAD(LAb, LAe, 0);
        GATE(1); PLOAD(LBb, LBe, 1);
        PWRITE(LAb, LAe, 0);
    }
    __syncthreads();

    // main: 14 x (even half, odd half); consumer handles chunks 0..27
    for (int c2 = 0; c2 < 14; ++c2) {
        const int c = c2 * 2;
        if (wv == 1) {
            GATE(c + 2); PLOAD(LAb, LAe, c + 2);
            PWRITE(LBb, LBe, 1);
        } else if (wv == 0) {
            CCHUNK(c, 0);
        }
        __syncthreads();
        if (wv == 1) {
            if (c2 < 13) { GATE(c + 3); PLOAD(LBb, LBe, c + 3); }
            PWRITE(LAb, LAe, 0);
        } else if (wv == 0) {
            CCHUNK(c + 1, 1);
        }
        __syncthreads();
    }
    // final chunk 28 (slot 0), consumer only; then finalize + fused mean
    if (wv == 0) {
        CCHUNK(28, 0);
        if (lane == 0) {
            // gate the final global read (row dcap+1, chunk dcap>>3)
            const int ckf = dcap >> 3;
            const int expf_ = chunk_expected(ckf);
            while (__hip_atomic_load(&cnt[b * 32 + ckf], __ATOMIC_ACQUIRE,
                                     __HIP_MEMORY_SCOPE_AGENT) < expf_)
                __builtin_amdgcn_s_sleep(1);
            float ll = cap + bB[(size_t)(dcap + 1) * DPAD + ul];
            nll[b] = -ll;
            int prev = __hip_atomic_fetch_add(dcnt, 1, __ATOMIC_ACQ_REL,
                                              __HIP_MEMORY_SCOPE_AGENT);
            if (prev == Bb - 1) {      // last dp block: write the mean
                float s = 0.0f;
                for (int i = 0; i < Bb; ++i)
                    s += __hip_atomic_load(&nll[i], __ATOMIC_RELAXED,
                                           __HIP_MEMORY_SCOPE_AGENT);
                out[0] = s / (float)Bb;
            }
        }
    }
#undef GATE
#undef PLOAD
#undef PWRITE
#undef CCHUNK
}

extern "C" void kernel_launch(void* const* d_in, const int* in_sizes, int n_in,
                              void* d_out, int out_size, void* d_ws, size_t ws_size,
                              hipStream_t stream) {
    const float* logits         = (const float*)d_in[0];
    const int*   targets        = (const int*)d_in[1];
    const int*   logit_lengths  = (const int*)d_in[2];
    const int*   target_lengths = (const int*)d_in[3];
    float* out = (float*)d_out;

    int*   cnt  = (int*)d_ws;                           // 8*32 ints
    int*   dcnt = cnt + 8 * 32;                         // 1 int
    float* base = (float*)d_ws + 512;
    float* bS   = base;                                 // 8*244*104 floats
    float* eS   = bS + (size_t)Bb * DROWS * DPAD;
    float* nll  = eS + (size_t)Bb * DROWS * DPAD;       // 8 floats

    // zero the counters (graph-capturable async op)
    hipMemsetAsync(d_ws, 0, 2048, stream);

    fused_kernel<<<NB_LSE + Bb, 256, 0, stream>>>(
        logits, targets, logit_lengths, target_lengths,
        cnt, dcnt, bS, eS, nll, out);
}

// Round 10
// 112.700 us; speedup vs baseline: 27.2375x; 27.2375x over previous
//
#include <hip/hip_runtime.h>
#include <hip/hip_fp16.h>

// RNN-T loss forward: B=8, T=128, U=100, V=1024, BLANK=0.
// out = mean_b of -( alpha[tl-2, ul] + blank_lp[tl-2, ul] )
//
// lse_kernel: log-softmax over V, scatter blank/emit log-probs (fp16) into
//   diagonal-major staging bS/eS (pitch 104 halves).
// dp_kernel: one block per batch, 9 waves. Waves 1..8 bulk-copy staging
//   region w (29 diagonal rows) global->LDS and release an LDS flag; wave 0
//   runs the 232-step anti-diagonal chain from LDS, acquiring each flag.
//   All sync is intra-block (LDS) — no cross-XCD atomics.

#define NEGV (-1e30f)

constexpr int Bb = 8;
constexpr int Tt = 128;
constexpr int Uu = 100;
constexpr int Vv = 1024;
constexpr int UP1 = Uu + 1;
constexpr int DROWS = 244;       // global staging rows per batch
constexpr int DPAD  = 104;       // staging row pitch (halves)
constexpr int LROWS = 233;       // LDS rows (d = 0..232; copied 1..232)
constexpr int REG   = 29;        // diagonals per copy region
constexpr int NREG  = 8;         // 8 regions * 29 = 232 diagonals

__device__ __forceinline__ float laddexp(float x, float y) {
    float m = fmaxf(x, y);
    float d = fabsf(x - y);
    return m + __logf(1.0f + __expf(-d));
}

// lane l receives lane l-1's value; lane 0 -> 0
__device__ __forceinline__ float wave_shr1(float x) {
    return __builtin_bit_cast(float, __builtin_amdgcn_update_dpp(
        0, __builtin_bit_cast(int, x), 0x138, 0xf, 0xf, true));
}

__device__ __forceinline__ float readlane_f(float x, int lane) {
    return __builtin_bit_cast(float,
        __builtin_amdgcn_readlane(__builtin_bit_cast(int, x), lane));
}

// Kernel 1: per (b,t,u) row of V=1024 logits compute lse; scatter fp16
// staging:  bS[b][d][u] = blank_lp[t][u],  eS[b][d][u+1] = emit_lp[t][u],
// both at d = t+u+1.
__global__ __launch_bounds__(256) void lse_kernel(
        const float* __restrict__ logits,
        const int*   __restrict__ targets,
        __half* __restrict__ bS,
        __half* __restrict__ eS) {
    const int wid  = blockIdx.x * 4 + (threadIdx.x >> 6);   // row index
    const int lane = threadIdx.x & 63;
    const int b   = wid / (Tt * UP1);
    const int rem = wid - b * (Tt * UP1);
    const int t   = rem / UP1;
    const int u   = rem - t * UP1;

    const float* row = logits + (size_t)wid * Vv;
    const float4* r4 = (const float4*)row;
    float4 x0 = r4[lane];
    float4 x1 = r4[lane + 64];
    float4 x2 = r4[lane + 128];
    float4 x3 = r4[lane + 192];

    float m = fmaxf(fmaxf(fmaxf(x0.x, x0.y), fmaxf(x0.z, x0.w)),
                    fmaxf(fmaxf(x1.x, x1.y), fmaxf(x1.z, x1.w)));
    m = fmaxf(m, fmaxf(fmaxf(fmaxf(x2.x, x2.y), fmaxf(x2.z, x2.w)),
                       fmaxf(fmaxf(x3.x, x3.y), fmaxf(x3.z, x3.w))));
    #pragma unroll
    for (int d = 32; d > 0; d >>= 1) m = fmaxf(m, __shfl_xor(m, d, 64));

    float s = __expf(x0.x - m) + __expf(x0.y - m) + __expf(x0.z - m) + __expf(x0.w - m)
            + __expf(x1.x - m) + __expf(x1.y - m) + __expf(x1.z - m) + __expf(x1.w - m)
            + __expf(x2.x - m) + __expf(x2.y - m) + __expf(x2.z - m) + __expf(x2.w - m)
            + __expf(x3.x - m) + __expf(x3.y - m) + __expf(x3.z - m) + __expf(x3.w - m);
    #pragma unroll
    for (int d = 32; d > 0; d >>= 1) s += __shfl_xor(s, d, 64);

    float lse = m + __logf(s);

    if (lane == 0) {
        const int dw = t + u + 1;                       // 1..228
        bS[((size_t)b * DROWS + dw) * DPAD + u] = __float2half(x0.x - lse);
        if (u < Uu) {
            int tgt = targets[b * Uu + u];
            eS[((size_t)b * DROWS + dw) * DPAD + (u + 1)] = __float2half(row[tgt] - lse);
        }
    }
}

// Kernel 2: one 576-thread block (9 waves) per batch element.
__global__ __launch_bounds__(576) void dp_kernel(
        const __half* __restrict__ bS,
        const __half* __restrict__ eS,
        const int*    __restrict__ logit_lengths,
        const int*    __restrict__ target_lengths,
        float* __restrict__ nll) {
    const int b    = blockIdx.x;
    const int tid  = threadIdx.x;
    const int wvi  = tid >> 6;          // 0 = consumer, 1..8 = copy waves
    const int lane = tid & 63;

    __shared__ __align__(16) __half lB[LROWS][DPAD];
    __shared__ __align__(16) __half lE[LROWS][DPAD];
    __shared__ int sflag[NREG];

    if (tid < NREG) sflag[tid] = 0;
    __syncthreads();

    const size_t bstride = (size_t)DROWS * DPAD;

    if (wvi >= 1) {
        // -------- copy wave: region w = rows [1+29w .. 29+29w], both arrays
        const int w = wvi - 1;
        const int row0 = 1 + REG * w;
        constexpr int RBYTES = REG * DPAD * 2;          // 6032 bytes
        const char* gb = (const char*)(bS + (size_t)b * bstride + (size_t)row0 * DPAD);
        const char* ge = (const char*)(eS + (size_t)b * bstride + (size_t)row0 * DPAD);
        char* db = (char*)&lB[row0][0];
        char* de = (char*)&lE[row0][0];
        for (int k = lane * 16; k < RBYTES; k += 64 * 16) {
            *(uint4*)(db + k) = *(const uint4*)(gb + k);
            *(uint4*)(de + k) = *(const uint4*)(ge + k);
        }
        __hip_atomic_store(&sflag[w], 1, __ATOMIC_RELEASE,
                           __HIP_MEMORY_SCOPE_WORKGROUP);
        return;
    }

    // -------- consumer wave: 232-step anti-diagonal chain from LDS --------
    const int tl = logit_lengths[b];
    const int ul = target_lengths[b];
    const int t_idx = tl - 2;           // reference reads alpha[tl-2][ul]
    const int dcap  = t_idx + ul;       // diagonal of the readout cell

    const int u0 = lane * 2, u1 = u0 + 1;
    float aP0 = (lane == 0) ? 0.0f : NEGV;   // alpha diag 0: only (0,0)=0
    float aP1 = NEGV;
    float cap = (dcap == 0) ? 0.0f : NEGV;

    for (int w = 0; w < NREG; ++w) {
        while (__hip_atomic_load(&sflag[w], __ATOMIC_ACQUIRE,
                                 __HIP_MEMORY_SCOPE_WORKGROUP) == 0)
            __builtin_amdgcn_s_sleep(1);
        __builtin_amdgcn_sched_barrier(0);

        const int dbase = 1 + REG * w;
        for (int j = 0; j < REG; ++j) {
            const int dv = dbase + j;
            const __half2 hB = *(const __half2*)&lB[dv][u0];
            const __half2 hE = *(const __half2*)&lE[dv][u0];
            const float2 Bf = __half22float2(hB);
            const float2 Ef = __half22float2(hE);
            float sh  = wave_shr1(aP1);
            float t1b = (u1 < dv) ? aP1 + Bf.y : NEGV;
            float t1e = aP0 + Ef.y;
            float t0b = (u0 < dv) ? aP0 + Bf.x : NEGV;
            float t0e = (lane >= 1) ? sh + Ef.x : NEGV;
            float n1 = laddexp(t1b, t1e);
            float n0 = laddexp(t0b, t0e);
            aP0 = n0; aP1 = n1;
            if (dv == dcap) {
                float w0 = readlane_f(n0, ul >> 1);
                float w1 = readlane_f(n1, ul >> 1);
                cap = (ul & 1) ? w1 : w0;
            }
        }
    }

    if (lane == 0) {
        // final blank term: row dcap+1 <= 227, already copied (all flags seen)
        float blk = __half2float(lB[dcap + 1][ul]);
        nll[b] = -(cap + blk);
    }
}

__global__ void mean_kernel(const float* __restrict__ nll, float* __restrict__ out) {
    if (threadIdx.x == 0 && blockIdx.x == 0) {
        float s = 0.0f;
        for (int i = 0; i < Bb; ++i) s += nll[i];
        out[0] = s / (float)Bb;
    }
}

extern "C" void kernel_launch(void* const* d_in, const int* in_sizes, int n_in,
                              void* d_out, int out_size, void* d_ws, size_t ws_size,
                              hipStream_t stream) {
    const float* logits         = (const float*)d_in[0];
    const int*   targets        = (const int*)d_in[1];
    const int*   logit_lengths  = (const int*)d_in[2];
    const int*   target_lengths = (const int*)d_in[3];
    float* out = (float*)d_out;

    __half* bS = (__half*)d_ws;                          // 8*244*104 halves
    __half* eS = bS + (size_t)Bb * DROWS * DPAD;
    float*  nll = (float*)(eS + (size_t)Bb * DROWS * DPAD);  // 8 floats

    const int rows = Bb * Tt * UP1;                     // 103424, divisible by 4
    lse_kernel<<<rows / 4, 256, 0, stream>>>(logits, targets, bS, eS);
    dp_kernel<<<Bb, 576, 0, stream>>>(bS, eS, logit_lengths, target_lengths, nll);
    mean_kernel<<<1, 64, 0, stream>>>(nll, out);
}